// Round 1
// 189.080 us; speedup vs baseline: 1.0678x; 1.0678x over previous
//
#include <hip/hip_runtime.h>

#define BATCH 65536
#define TB 32

typedef _Float16 half8 __attribute__((ext_vector_type(8)));
typedef _Float16 half4v __attribute__((ext_vector_type(4)));
typedef _Float16 half2v __attribute__((ext_vector_type(2)));
typedef float fx4 __attribute__((ext_vector_type(4)));

// workspace layout (halves) -- unchanged from R12
#define PW1B_OFF 0        // [4][256][32]  W1 base rows (k<110, pad->128)
#define PW1F_OFF 32768    // [256][32]     W1 feat rows, k-map [feat_i(15) 0 feat_j(15) 0]
#define PW2_OFF  40960    // [8][256][32]
#define PWR_OFF  106496   // [8][256][32]
#define PWH_OFF  172032   // [8][16][32]   [mean_w | lstd_w | pad]
#define WS_TOTAL 176128

__global__ __launch_bounds__(256) void prep_weights(
    const float* __restrict__ w1, const float* __restrict__ w2,
    const float* __restrict__ wr, const float* __restrict__ wm,
    const float* __restrict__ wl, _Float16* __restrict__ ws)
{
  int idx = blockIdx.x * 256 + threadIdx.x;
  if (idx < 32768) {            // pw1b
    int kk = idx & 31, n = (idx >> 5) & 255, kt = idx >> 13;
    int k = kt * 32 + kk;
    ws[idx] = (k < 110) ? (_Float16)w1[k * 256 + n] : (_Float16)0.f;
  } else if (idx < 40960) {     // pw1f
    int t = idx - 32768;
    int kk = t & 31, n = t >> 5;
    _Float16 v = (_Float16)0.f;
    if (kk < 15)                  v = (_Float16)w1[(113 + kk) * 256 + n];
    else if (kk >= 16 && kk < 31) v = (_Float16)w1[(131 + (kk - 16)) * 256 + n];
    ws[idx] = v;
  } else if (idx < 106496) {    // pw2
    int t = idx - 40960;
    int kk = t & 31, n = (t >> 5) & 255, kt = t >> 13;
    ws[idx] = (_Float16)w2[(kt * 32 + kk) * 256 + n];
  } else if (idx < 172032) {    // pwr
    int t = idx - 106496;
    int kk = t & 31, n = (t >> 5) & 255, kt = t >> 13;
    ws[idx] = (_Float16)wr[(kt * 32 + kk) * 256 + n];
  } else if (idx < WS_TOTAL) {  // pwh
    int t = idx - 172032;
    int kk = t & 31, n = (t >> 5) & 15, kt = t >> 9;
    int k = kt * 32 + kk;
    _Float16 v = (_Float16)0.f;
    if (n < 4) v = (_Float16)wm[k * 4 + n];
    else if (n < 8) v = (_Float16)wl[k * 4 + (n - 4)];
    ws[PWH_OFF + t] = v;
  }
}

// R13: TB=32 + perm-split GEMM2 (3+3 over the same 48KB H1) + operand-swapped
// MFMA (mfma(W,x): D = (x@W)^T tile; lane holds 4 CONSECUTIVE out-cols at a
// fixed batch row) so every LDS epilogue write is a packed b64 instead of 4
// scalar u16, bias reads are float4, head stores are coalesced float4.
// LDS layout lin(r,c) = ((c>>3)*R + r)*8 + (c&7)  (== old HIDX for R=16).
// Readers (A-fragment ds_read_b128) unchanged. LDS = 48+16+3+6 = 73 KB ->
// 2 blocks/CU; __launch_bounds__(512,4) pins VGPR<=128 to keep it.
__global__ __launch_bounds__(512, 4) void actor_fused(
    const float* __restrict__ obs, const float* __restrict__ lemb,
    const float* __restrict__ w1, const _Float16* __restrict__ ws,
    const float* __restrict__ b1, const float* __restrict__ b2,
    const float* __restrict__ br, const float* __restrict__ bm,
    const float* __restrict__ bl, float* __restrict__ out)
{
  __shared__ __align__(16) _Float16 H1[6 * 16 * 256]; // 48 KB: 6 tiles (pp*2+rt); tiles 0,1 later r
  __shared__ __align__(16) _Float16 Bb[32 * 256];     // 16 KB: base (K=128), later agg (K=256)
  __shared__ __align__(16) _Float16 Os[3 * 32 * 16];  //  3 KB: compact obj tiles
  __shared__ __align__(16) float    Bsf[6 * 256];     //  6 KB: fused per-perm biases (f32)

  const _Float16* __restrict__ pw1b = ws + PW1B_OFF;
  const _Float16* __restrict__ pw1f = ws + PW1F_OFF;
  const _Float16* __restrict__ pw2  = ws + PW2_OFF;
  const _Float16* __restrict__ pwr  = ws + PWR_OFF;
  const _Float16* __restrict__ pwh  = ws + PWH_OFF;

  const int tid  = threadIdx.x;
  const int wave = tid >> 6;        // 0..7
  const int lane = tid & 63;
  const int q    = lane >> 4;
  const int l16  = lane & 15;
  const int colbase = wave * 32;    // this wave's 32 output cols
  const int rowbase = blockIdx.x * TB;

  const int c0_0 = colbase + q * 4;        // start col of this lane's 4-col pack, nt=0
  const int c0_1 = colbase + 16 + q * 4;   // nt=1

  // ---- stage base (32 rows x K=128) into Bb as 64 col-pairs/row ----
  for (int idx = tid; idx < 2048; idx += 512) {
    int r = idx >> 6, c2 = idx & 63, c = c2 * 2;
    float v0 = 0.f, v1 = 0.f;
    if (c2 < 50) {
      float2 v = ((const float2*)(lemb + (rowbase + r) * 100))[c2];
      v0 = v.x; v1 = v.y;
    } else if (c < 110) {
      v0 = obs[(rowbase + r) * 55 + (c - 100)];
      v1 = (c + 1 < 110) ? obs[(rowbase + r) * 55 + (c - 99)] : 0.f;
    }
    half2v hv = {(_Float16)v0, (_Float16)v1};
    *(half2v*)&Bb[((c >> 3) * 32 + r) * 8 + (c & 7)] = hv;
  }
  // ---- compact obj tiles: 3 objects x 32 rows x 16 k (15 feats + pad) ----
  for (int idx = tid; idx < 1536; idx += 512) {
    int o = idx >> 9, rem = idx & 511, r = rem >> 4, k = rem & 15;
    float v = (k < 15) ? obs[(rowbase + r) * 55 + 10 + o * 15 + k] : 0.f;
    Os[o * 512 + ((k >> 3) * 32 + r) * 8 + (k & 7)] = (_Float16)v;
  }
  // ---- fused per-perm biases (f32): b1 + W1[onehot_i row] + W1[onehot_j row] ----
  for (int idx = tid; idx < 1536; idx += 512) {
    int p = idx >> 8, c = idx & 255;
    int oi = p >> 1, oj = (1161 >> (2 * p)) & 3;
    Bsf[idx] = b1[c] + w1[(110 + oi) * 256 + c] + w1[(128 + oj) * 256 + c];
  }
  __syncthreads();  // B1

  const fx4 zero4 = {0.f, 0.f, 0.f, 0.f};

  // ---- U = (base @ W1base)^T tiles (K=128), 2 row-halves x 2 col-halves ----
  fx4 u[4];  // [rt*2+nt]
  u[0] = zero4; u[1] = zero4; u[2] = zero4; u[3] = zero4;
  #pragma unroll
  for (int kt = 0; kt < 4; ++kt) {
    half8 a0 = *(const half8*)&Bb[((kt * 4 + q) * 32 + l16) * 8];
    half8 a1 = *(const half8*)&Bb[((kt * 4 + q) * 32 + 16 + l16) * 8];
    #pragma unroll
    for (int nt = 0; nt < 2; ++nt) {
      half8 b = *(const half8*)&pw1b[(kt * 256 + colbase + nt * 16 + l16) * 32 + q * 8];
      u[nt]     = __builtin_amdgcn_mfma_f32_16x16x32_f16(b, a0, u[nt], 0, 0, 0);
      u[2 + nt] = __builtin_amdgcn_mfma_f32_16x16x32_f16(b, a1, u[2 + nt], 0, 0, 0);
    }
  }
  // no barrier: Bb not rewritten until agg store; H1 unread so far

  // ---- GEMM1 group: h1_p = relu(U + F_p @ W1f + bias_p) for 3 perms ----
  // swapped D: lane holds rows l16 (batch), cols c0..c0+3 -> packed b64 store
  auto g1_group = [&](int g) {
    half8 b1f0 = *(const half8*)&pw1f[(colbase + l16) * 32 + q * 8];
    half8 b1f1 = *(const half8*)&pw1f[(colbase + 16 + l16) * 32 + q * 8];
    #pragma unroll
    for (int pp = 0; pp < 3; ++pp) {
      const int p = g * 3 + pp;
      const int oi = p >> 1, oj = (1161 >> (2 * p)) & 3;
      const int o = (q < 2) ? oi : oj;   // quads 0,1 -> feat_i; 2,3 -> feat_j
      #pragma unroll
      for (int rt = 0; rt < 2; ++rt) {
        half8 af = *(const half8*)&Os[o * 512 + ((q & 1) * 32 + rt * 16 + l16) * 8];
        #pragma unroll
        for (int nt = 0; nt < 2; ++nt) {
          fx4 t = __builtin_amdgcn_mfma_f32_16x16x32_f16(nt ? b1f1 : b1f0, af,
                                                         u[rt * 2 + nt], 0, 0, 0);
          const int c0 = nt ? c0_1 : c0_0;
          fx4 bs = *(const fx4*)&Bsf[p * 256 + c0];
          float h0 = fmaxf(t[0] + bs[0], 0.f);
          float h1v = fmaxf(t[1] + bs[1], 0.f);
          float h2v = fmaxf(t[2] + bs[2], 0.f);
          float h3v = fmaxf(t[3] + bs[3], 0.f);
          half4v hv = {(_Float16)h0, (_Float16)h1v, (_Float16)h2v, (_Float16)h3v};
          *(half4v*)&H1[(pp * 2 + rt) * 4096 + ((c0 >> 3) * 16 + l16) * 8 + (c0 & 7)] = hv;
        }
      }
    }
  };

  // ---- GEMM2 group: 6 tiles (3p x 2rt), K=256, bias-folded init ----
  fx4 agg[4];  // [rt*2+nt]
  agg[0] = zero4; agg[1] = zero4; agg[2] = zero4; agg[3] = zero4;
  fx4 b2v[2];
  b2v[0] = *(const fx4*)&b2[c0_0];
  b2v[1] = *(const fx4*)&b2[c0_1];

  auto g2_group = [&]() {
    fx4 acc[12];
    #pragma unroll
    for (int i = 0; i < 12; ++i) acc[i] = b2v[i & 1];
    #pragma unroll 2
    for (int kt = 0; kt < 8; ++kt) {
      half8 bb0 = *(const half8*)&pw2[(kt * 256 + colbase + l16) * 32 + q * 8];
      half8 bb1 = *(const half8*)&pw2[(kt * 256 + colbase + 16 + l16) * 32 + q * 8];
      #pragma unroll
      for (int t6 = 0; t6 < 6; ++t6) {
        half8 a = *(const half8*)&H1[t6 * 4096 + ((kt * 4 + q) * 16 + l16) * 8];
        acc[t6 * 2]     = __builtin_amdgcn_mfma_f32_16x16x32_f16(bb0, a, acc[t6 * 2], 0, 0, 0);
        acc[t6 * 2 + 1] = __builtin_amdgcn_mfma_f32_16x16x32_f16(bb1, a, acc[t6 * 2 + 1], 0, 0, 0);
      }
    }
    #pragma unroll
    for (int t6 = 0; t6 < 6; ++t6)
      #pragma unroll
      for (int nt = 0; nt < 2; ++nt)
        #pragma unroll
        for (int rr = 0; rr < 4; ++rr) {
          float h = acc[t6 * 2 + nt][rr];
          if (h > 0.f) agg[(t6 & 1) * 2 + nt][rr] += h;
        }
  };

  g1_group(0);
  __syncthreads();  // B2: h1 tiles (perms 0-2) ready
  g2_group();
  __syncthreads();  // B3: all H1 reads of group 0 done
  g1_group(1);
  __syncthreads();  // B4: h1 tiles (perms 3-5) ready
  g2_group();

  // stage agg into Bb (base region dead since U; all waves past B4 > U)
  #pragma unroll
  for (int rt = 0; rt < 2; ++rt)
    #pragma unroll
    for (int nt = 0; nt < 2; ++nt) {
      const int c0 = nt ? c0_1 : c0_0;
      fx4 t = agg[rt * 2 + nt];
      half4v hv = {(_Float16)t[0], (_Float16)t[1], (_Float16)t[2], (_Float16)t[3]};
      *(half4v*)&Bb[((c0 >> 3) * 32 + rt * 16 + l16) * 8 + (c0 & 7)] = hv;
    }
  __syncthreads();  // B5: agg complete in Bb

  // ---- GEMM3: r = relu(agg @ rho + br), M=32, K=256; r -> H1 tiles 0,1 ----
  fx4 acc3[4];  // [rt*2+nt]
  {
    fx4 brv0 = *(const fx4*)&br[c0_0];
    fx4 brv1 = *(const fx4*)&br[c0_1];
    acc3[0] = brv0; acc3[1] = brv1; acc3[2] = brv0; acc3[3] = brv1;
  }
  #pragma unroll 2
  for (int kt = 0; kt < 8; ++kt) {
    half8 a0 = *(const half8*)&Bb[((kt * 4 + q) * 32 + l16) * 8];
    half8 a1 = *(const half8*)&Bb[((kt * 4 + q) * 32 + 16 + l16) * 8];
    #pragma unroll
    for (int nt = 0; nt < 2; ++nt) {
      half8 b = *(const half8*)&pwr[(kt * 256 + colbase + nt * 16 + l16) * 32 + q * 8];
      acc3[nt]     = __builtin_amdgcn_mfma_f32_16x16x32_f16(b, a0, acc3[nt], 0, 0, 0);
      acc3[2 + nt] = __builtin_amdgcn_mfma_f32_16x16x32_f16(b, a1, acc3[2 + nt], 0, 0, 0);
    }
  }
  #pragma unroll
  for (int rt = 0; rt < 2; ++rt)
    #pragma unroll
    for (int nt = 0; nt < 2; ++nt) {
      const int c0 = nt ? c0_1 : c0_0;
      fx4 t = acc3[rt * 2 + nt];
      half4v hv = {(_Float16)fmaxf(t[0], 0.f), (_Float16)fmaxf(t[1], 0.f),
                   (_Float16)fmaxf(t[2], 0.f), (_Float16)fmaxf(t[3], 0.f)};
      *(half4v*)&H1[rt * 4096 + ((c0 >> 3) * 16 + l16) * 8 + (c0 & 7)] = hv;
    }
  __syncthreads();  // B6: r ready

  // ---- heads: waves 0,1 (one row-half each); swapped D -> float4 stores ----
  if (wave < 2) {
    fx4 a4 = zero4;
    #pragma unroll 2
    for (int kt = 0; kt < 8; ++kt) {
      half8 rfrag = *(const half8*)&H1[wave * 4096 + ((kt * 4 + q) * 16 + l16) * 8];
      half8 wfrag = *(const half8*)&pwh[(kt * 16 + l16) * 32 + q * 8];
      a4 = __builtin_amdgcn_mfma_f32_16x16x32_f16(wfrag, rfrag, a4, 0, 0, 0);
    }
    const int row = rowbase + wave * 16 + l16;
    if (q == 0) {            // head cols 0..3 = mean
      fx4 bm4 = *(const fx4*)bm;
      fx4 o = {a4[0] + bm4[0], a4[1] + bm4[1], a4[2] + bm4[2], a4[3] + bm4[3]};
      *(fx4*)&out[row * 4] = o;
    } else if (q == 1) {     // head cols 4..7 = log_std (clipped)
      fx4 bl4 = *(const fx4*)bl;
      fx4 o;
      #pragma unroll
      for (int rr = 0; rr < 4; ++rr) {
        float v = a4[rr] + bl4[rr];
        o[rr] = v < -20.f ? -20.f : (v > 2.f ? 2.f : v);
      }
      *(fx4*)&out[BATCH * 4 + row * 4] = o;
    }
  }
}

extern "C" void kernel_launch(void* const* d_in, const int* in_sizes, int n_in,
                              void* d_out, int out_size, void* d_ws, size_t ws_size,
                              hipStream_t stream) {
  const float* obs  = (const float*)d_in[0];
  const float* lemb = (const float*)d_in[1];
  const float* w1   = (const float*)d_in[2];
  const float* b1   = (const float*)d_in[3];
  const float* w2   = (const float*)d_in[4];
  const float* b2   = (const float*)d_in[5];
  const float* wr   = (const float*)d_in[6];
  const float* br   = (const float*)d_in[7];
  const float* wm   = (const float*)d_in[8];
  const float* bm   = (const float*)d_in[9];
  const float* wl   = (const float*)d_in[10];
  const float* bl   = (const float*)d_in[11];
  float* out = (float*)d_out;
  _Float16* ws = (_Float16*)d_ws;

  hipLaunchKernelGGL(prep_weights, dim3(WS_TOTAL / 256), dim3(256), 0, stream,
                     w1, w2, wr, wm, wl, ws);
  hipLaunchKernelGGL(actor_fused, dim3(BATCH / TB), dim3(512), 0, stream,
                     obs, lemb, w1, (const _Float16*)ws, b1, b2, br, bm, bl, out);
}